// Round 13
// baseline (603.073 us; speedup 1.0000x reference)
//
#include <hip/hip_runtime.h>

#define HIDDEN 1024
#define FF 2048
#define NEXP 8
#define NTOK 16384
#define NPAIR (2 * NTOK)
#define MAXT 264   // sum_e ceil(cnt[e]/128) <= 256 + 8

typedef short short8 __attribute__((ext_vector_type(8)));
typedef unsigned short ushort4v __attribute__((ext_vector_type(4)));
typedef float f32x4 __attribute__((ext_vector_type(4)));
typedef float f32x16 __attribute__((ext_vector_type(16)));

// fp32 -> bf16 bits, round-to-nearest-even
__device__ __forceinline__ unsigned short f2b(float f) {
  union { float f; unsigned int u; } v; v.f = f;
  unsigned int u = v.u;
  return (unsigned short)((u + 0x7fffu + ((u >> 16) & 1u)) >> 16);
}

// async global->LDS, 16B per lane. LDS dest = wave-uniform base + lane*16.
__device__ __forceinline__ void gload16(const unsigned short* g, unsigned short* l) {
  __builtin_amdgcn_global_load_lds(
      (const __attribute__((address_space(1))) unsigned int*)g,
      (__attribute__((address_space(3))) unsigned int*)l,
      16, 0, 0);
}

// counted vmcnt waits: asm memory clobber (compiler fence) + sched fence (rule 18)
#define PIPE_WAIT(n) do { \
    asm volatile("s_waitcnt vmcnt(" #n ")" ::: "memory"); \
    __builtin_amdgcn_sched_barrier(0); \
  } while (0)
// raw barrier that IS a compiler memory fence, plus sched fence
#define ABAR do { \
    asm volatile("s_barrier" ::: "memory"); \
    __builtin_amdgcn_sched_barrier(0); \
  } while (0)

// ---------------- workspace layout (bytes) ----------------
#define W1T_OFF 0ull                                                      // [E][FF][HIDDEN] bf16, 32MB
#define W2T_OFF (W1T_OFF + (unsigned long long)NEXP * FF * HIDDEN * 2)    // [E][HIDDEN][FF] bf16, 32MB
#define H_OFF   (W2T_OFF + (unsigned long long)NEXP * HIDDEN * FF * 2)    // [NPAIR][FF] bf16, 128MB
#define XB_OFF  (H_OFF + (unsigned long long)NPAIR * FF * 2)              // [NTOK][HIDDEN] bf16, 32MB
#define CNT_OFF (XB_OFF + (unsigned long long)NTOK * HIDDEN * 2)          // [E] int
#define PLIST_OFF (CNT_OFF + 256ull)                                      // [E][NTOK] int
#define PW_OFF    (PLIST_OFF + (unsigned long long)NEXP * NTOK * 4)       // [NPAIR] float
#define TOPS_OFF  (PW_OFF + (unsigned long long)NPAIR * 4)                // [NTOK] int
#define W0_OFF    (TOPS_OFF + (unsigned long long)NTOK * 4)               // [NTOK] float
#define WQ_OFF    (W0_OFF + (unsigned long long)NTOK * 4)                 // [MAXT] int

// zero out with our own kernel: hipMemsetAsync inside kernel_launch is NOT
// replayed reliably under graph capture (R10 post-timing re-validation fail).
__global__ void zero_out_k(float4* __restrict__ out) {
  out[(size_t)blockIdx.x * 256 + threadIdx.x] = float4{0.f, 0.f, 0.f, 0.f};
}

__global__ void zero_cnt_k(int* __restrict__ cnt) {
  if (threadIdx.x < NEXP) cnt[threadIdx.x] = 0;
}

// in: [E][R][C] f32  ->  out: [E][C][R] bf16
__global__ void transpose_cast_k(const float* __restrict__ in,
                                 unsigned short* __restrict__ out,
                                 int R, int C) {
  __shared__ float tile[32][33];
  const size_t eoff = (size_t)blockIdx.z * R * C;
  const float* inp = in + eoff;
  unsigned short* outp = out + eoff;
  const int c = threadIdx.x & 31;
  const int r0 = threadIdx.x >> 5;
  const int gr = blockIdx.y * 32, gc = blockIdx.x * 32;
#pragma unroll
  for (int i = 0; i < 4; i++) {
    int r = r0 + i * 8;
    tile[r][c] = inp[(size_t)(gr + r) * C + gc + c];
  }
  __syncthreads();
#pragma unroll
  for (int i = 0; i < 4; i++) {
    int r = r0 + i * 8;
    outp[(size_t)(gc + r) * R + gr + c] = f2b(tile[c][r]);
  }
}

// one wave per token: logits over 8 experts, top-2, renorm; fused x->bf16 cast.
__global__ void router_k(const float* __restrict__ x, const float* __restrict__ rw,
                         const float* __restrict__ rb, int* __restrict__ tops,
                         float* __restrict__ w0f, unsigned short* __restrict__ xb) {
  const int wid = threadIdx.x >> 6;
  const int lane = threadIdx.x & 63;
  const int t = blockIdx.x * 4 + wid;
  const float* xr = x + (size_t)t * HIDDEN;
  float acc[8];
#pragma unroll
  for (int e = 0; e < 8; e++) acc[e] = 0.f;
#pragma unroll
  for (int i = 0; i < 16; i++) {
    int hh = lane + 64 * i;
    float xv = xr[hh];
    const float4* rwp = reinterpret_cast<const float4*>(rw + (size_t)hh * 8);
    float4 a = rwp[0], b = rwp[1];
    acc[0] += xv * a.x; acc[1] += xv * a.y; acc[2] += xv * a.z; acc[3] += xv * a.w;
    acc[4] += xv * b.x; acc[5] += xv * b.y; acc[6] += xv * b.z; acc[7] += xv * b.w;
  }
  // fused cast: x row -> xb row (vectorized, L2-hot after the dot loop)
  {
    const float4* xr4 = reinterpret_cast<const float4*>(xr);
    unsigned short* xbr = xb + (size_t)t * HIDDEN;
#pragma unroll
    for (int i = 0; i < 4; i++) {
      float4 f = xr4[lane + 64 * i];
      ushort4v o;
      o[0] = f2b(f.x); o[1] = f2b(f.y); o[2] = f2b(f.z); o[3] = f2b(f.w);
      *reinterpret_cast<ushort4v*>(&xbr[(lane + 64 * i) * 4]) = o;
    }
  }
#pragma unroll
  for (int off = 32; off; off >>= 1) {
#pragma unroll
    for (int e = 0; e < 8; e++) acc[e] += __shfl_xor(acc[e], off);
  }
  if (lane == 0) {
#pragma unroll
    for (int e = 0; e < 8; e++) acc[e] += rb[e];
    int i0 = 0; float m0 = acc[0];
#pragma unroll
    for (int e = 1; e < 8; e++) if (acc[e] > m0) { m0 = acc[e]; i0 = e; }
    int i1 = -1; float m1 = -1e30f;
#pragma unroll
    for (int e = 0; e < 8; e++) if (e != i0 && acc[e] > m1) { m1 = acc[e]; i1 = e; }
    float w0 = 1.f / (1.f + __expf(m1 - m0));
    tops[t] = i0 | (i1 << 4);
    w0f[t] = w0;
  }
}

// block-aggregated scatter: 256 tokens/block, LDS histogram, 8 global atomics/block
__global__ __launch_bounds__(256)
void scatter_k(const int* __restrict__ tops, const float* __restrict__ w0f,
               int* __restrict__ cnt, int* __restrict__ plist, float* __restrict__ pw) {
  __shared__ int lcnt[NEXP];
  __shared__ int lbase[NEXP];
  const int tid = threadIdx.x;
  const int t = blockIdx.x * 256 + tid;
  if (tid < NEXP) lcnt[tid] = 0;
  __syncthreads();
  const int packed = tops[t];
  const int i0 = packed & 15, i1 = packed >> 4;
  const float w0 = w0f[t];
  const int s0 = atomicAdd(&lcnt[i0], 1);
  const int s1 = atomicAdd(&lcnt[i1], 1);
  __syncthreads();
  if (tid < NEXP) lbase[tid] = atomicAdd(&cnt[tid], lcnt[tid]);
  __syncthreads();
  plist[i0 * NTOK + lbase[i0] + s0] = 2 * t;
  plist[i1 * NTOK + lbase[i1] + s1] = 2 * t + 1;
  pw[2 * t] = w0;
  pw[2 * t + 1] = 1.f - w0;
}

// build compact (expert, 128-row m-tile) work list
__global__ void plan_k(const int* __restrict__ cnt, int* __restrict__ workq) {
  if (threadIdx.x == 0) {
    int idx = 0;
    for (int e = 0; e < NEXP; e++) {
      int nt = (cnt[e] + 127) >> 7;
      for (int m = 0; m < nt; m++) workq[idx++] = (e << 16) | m;
    }
    while (idx < MAXT) workq[idx++] = -1;
  }
}

// Grouped GEMM, 128x128 tile, 4 waves, BK=32, 3-deep counted-vmcnt pipeline
// (R8/R11-proven skeleton, unchanged) with 32x32x16 MFMA (half the MFMA
// instructions, ~20% less matrix-pipe time, 2382 vs 2075 TF ceiling).
// Wave tile 64x64 = 2x2 frags of 32x32. Per K-tile: kk in {0,1} k-slices of
// 16; af/bf = 16B/lane (row=l&31, k0=(l>>5)*8 — mirrors the verified
// 16x16x32 pattern); C/D: col=lane&31, row=(reg&3)+8*(reg>>2)+4*(lane>>5)
// [m74/m101-verified]. Staging + 4-slot both-sides swizzle identical to R11.
// PHASE 1: h[pair] = relu(xb[token] @ w1t[e]^T + b1[e])  (K=1024,N=2048)
// PHASE 2: out[token] += pw[pair] * (h[pair] @ w2t[e]^T + b2[e]) (K=2048,N=1024)
template <int PHASE>
__global__ __launch_bounds__(256, 3)
void ffn_k(const unsigned short* __restrict__ xb, const unsigned short* __restrict__ wT,
           const float* __restrict__ bias, const unsigned short* __restrict__ hin,
           unsigned short* __restrict__ hout, float* __restrict__ out,
           const int* __restrict__ cnt, const int* __restrict__ plist,
           const float* __restrict__ pw, const int* __restrict__ workq) {
  constexpr int K = (PHASE == 1) ? HIDDEN : FF;
  constexpr int N = (PHASE == 1) ? FF : HIDDEN;
  constexpr int NT = K / 32;
  constexpr int NTN = N / 128;
  constexpr int NWG = MAXT * NTN;

  // bijective XCD swizzle (m204): XCD k gets a contiguous wgid chunk
  constexpr int q8 = NWG / 8, r8 = NWG % 8;
  const int bid = blockIdx.x;
  const int xcd = bid & 7, idx = bid >> 3;
  const int wgid = (xcd < r8 ? xcd * (q8 + 1) : r8 * (q8 + 1) + (xcd - r8) * q8) + idx;
  const int mt = wgid / NTN;
  const int n0g = (wgid % NTN) * 128;

  const int w = workq[mt];
  if (w < 0) return;
  const int e = w >> 16;
  const int m0g = (w & 0xffff) * 128;
  const int mcnt = cnt[e];
  const int mrem = mcnt - m0g;

  // triple-buffered linear LDS: 6 x 8 KB = 48 KB
  __shared__ alignas(16) unsigned short As[3][128][32];
  __shared__ alignas(16) unsigned short Bs[3][128][32];
  __shared__ int rowpair[128];

  const int tid = threadIdx.x;
  if (tid < 128) rowpair[tid] = (tid < mrem) ? plist[e * NTOK + m0g + tid] : -1;
  __syncthreads();

  const int wid = tid >> 6;
  const int lane = tid & 63;

  // staging: chunk c (0..7) = LDS rows [c*16, c*16+16). lane l -> row c*16+(l>>2),
  // LDS slot (l&3); GLOBAL slot pre-swizzled: (l&3)^((l>>2)&3). 4 gloads/wave/tile.
  const int sslot = (lane & 3) ^ ((lane >> 2) & 3);
  const int rsub = lane >> 2;
  const unsigned short* wTe = wT + (size_t)e * N * K;

  const unsigned short* gA[2];
  const unsigned short* gB[2];
#pragma unroll
  for (int i = 0; i < 2; i++) {
    const int c = wid + i * 4;
    const int row = c * 16 + rsub;
    int p = rowpair[row];
    if (p < 0) p = 0;  // dummy valid row; its acc rows are never written
    const unsigned short* abase;
    if constexpr (PHASE == 1) abase = xb + (size_t)(p >> 1) * HIDDEN;
    else                      abase = hin + (size_t)p * FF;
    gA[i] = abase + sslot * 8;
    gB[i] = wTe + (size_t)(n0g + row) * K + sslot * 8;
  }

  const int wr = (wid >> 1) * 64;
  const int wc = (wid & 1) * 64;
  const int fr32 = lane & 31;        // frag row/col within 32x32
  const int fg2 = lane >> 5;         // k-half selector (0,1)
  const int fsw = fr32 & 3;          // read-side swizzle term (matches staging)

  f32x16 acc[2][2];
#pragma unroll
  for (int i = 0; i < 2; i++)
#pragma unroll
    for (int j = 0; j < 2; j++)
#pragma unroll
      for (int r = 0; r < 16; r++) acc[i][j][r] = 0.f;

  // ---- prologue: tiles 0,1,2 -> bufs 0,1,2 (12 loads in flight per wave) ----
#pragma unroll
  for (int b = 0; b < 3; b++) {
#pragma unroll
    for (int i = 0; i < 2; i++) {
      const int c = wid + i * 4;
      gload16(gA[i] + b * 32, &As[b][c * 16][0]);
      gload16(gB[i] + b * 32, &Bs[b][c * 16][0]);
    }
  }

  int cur = 0;
  for (int t = 0; t < NT; ++t) {
    if (t < NT - 2)       PIPE_WAIT(8);  // tile t done; t+1,t+2 stay in flight
    else if (t == NT - 2) PIPE_WAIT(4);
    else                  PIPE_WAIT(0);
    ABAR;  // all waves' tile-t loads now visible

    // kk = k-slice of 16 within the 32-wide tile; global slot = kk*2+fg2
#pragma unroll
    for (int kk = 0; kk < 2; kk++) {
      short8 af[2], bf[2];
#pragma unroll
      for (int mi = 0; mi < 2; mi++)
        af[mi] = *(const short8*)&As[cur][wr + mi * 32 + fr32][(((kk * 2 + fg2)) ^ fsw) * 8];
#pragma unroll
      for (int ni = 0; ni < 2; ni++)
        bf[ni] = *(const short8*)&Bs[cur][wc + ni * 32 + fr32][(((kk * 2 + fg2)) ^ fsw) * 8];
#pragma unroll
      for (int mi = 0; mi < 2; mi++)
#pragma unroll
        for (int ni = 0; ni < 2; ni++)
          acc[mi][ni] = __builtin_amdgcn_mfma_f32_32x32x16_bf16(af[mi], bf[ni], acc[mi][ni], 0, 0, 0);
    }

    ABAR;  // all waves done READING buf[cur]; safe to overwrite

    if (t + 3 < NT) {
      const int kt = (t + 3) * 32;
#pragma unroll
      for (int i = 0; i < 2; i++) {
        const int c = wid + i * 4;
        gload16(gA[i] + kt, &As[cur][c * 16][0]);
        gload16(gB[i] + kt, &Bs[cur][c * 16][0]);
      }
    }
    cur = (cur == 2) ? 0 : cur + 1;
  }

  // ---- epilogue ----
  // C/D layout: col = wc + ni*32 + fr32; row = wr + mi*32 + (reg&3) + 8*(reg>>2) + 4*fg2
  float bv[2];
#pragma unroll
  for (int ni = 0; ni < 2; ni++) bv[ni] = bias[(size_t)e * N + n0g + wc + ni * 32 + fr32];

#pragma unroll
  for (int mi = 0; mi < 2; mi++) {
#pragma unroll
    for (int reg = 0; reg < 16; reg++) {
      const int m = wr + mi * 32 + (reg & 3) + 8 * (reg >> 2) + 4 * fg2;
      if (m >= mrem) continue;
      const int p = rowpair[m];
      if constexpr (PHASE == 1) {
        unsigned short* hr = hout + (size_t)p * FF + n0g;
#pragma unroll
        for (int ni = 0; ni < 2; ni++) {
          float v = acc[mi][ni][reg] + bv[ni];
          hr[wc + ni * 32 + fr32] = f2b(fmaxf(v, 0.f));
        }
      } else {
        const float wgt = pw[p];
        float* orow = out + (size_t)(p >> 1) * HIDDEN + n0g;
#pragma unroll
        for (int ni = 0; ni < 2; ni++) {
          float v = (acc[mi][ni][reg] + bv[ni]) * wgt;
          atomicAdd(&orow[wc + ni * 32 + fr32], v);
        }
      }
    }
  }
}

extern "C" void kernel_launch(void* const* d_in, const int* in_sizes, int n_in,
                              void* d_out, int out_size, void* d_ws, size_t ws_size,
                              hipStream_t stream) {
  const float* x  = (const float*)d_in[0];
  const float* rw = (const float*)d_in[1];
  const float* rb = (const float*)d_in[2];
  const float* w1 = (const float*)d_in[3];
  const float* b1 = (const float*)d_in[4];
  const float* w2 = (const float*)d_in[5];
  const float* b2 = (const float*)d_in[6];
  float* out = (float*)d_out;
  char* ws = (char*)d_ws;

  unsigned short* w1t = (unsigned short*)(ws + W1T_OFF);
  unsigned short* w2t = (unsigned short*)(ws + W2T_OFF);
  unsigned short* h   = (unsigned short*)(ws + H_OFF);
  unsigned short* xb  = (unsigned short*)(ws + XB_OFF);
  int* cnt   = (int*)(ws + CNT_OFF);
  int* plist = (int*)(ws + PLIST_OFF);
  float* pwt = (float*)(ws + PW_OFF);
  int* tops  = (int*)(ws + TOPS_OFF);
  float* w0f = (float*)(ws + W0_OFF);
  int* workq = (int*)(ws + WQ_OFF);

  hipLaunchKernelGGL(zero_cnt_k, dim3(1), dim3(64), 0, stream, cnt);
  hipLaunchKernelGGL(zero_out_k, dim3(16384), dim3(256), 0, stream, (float4*)out);
  hipLaunchKernelGGL(transpose_cast_k, dim3(FF / 32, HIDDEN / 32, NEXP), dim3(256), 0, stream,
                     w1, w1t, HIDDEN, FF);
  hipLaunchKernelGGL(transpose_cast_k, dim3(HIDDEN / 32, FF / 32, NEXP), dim3(256), 0, stream,
                     w2, w2t, FF, HIDDEN);
  hipLaunchKernelGGL(router_k, dim3(NTOK / 4), dim3(256), 0, stream, x, rw, rb, tops, w0f, xb);
  hipLaunchKernelGGL(scatter_k, dim3(NTOK / 256), dim3(256), 0, stream, tops, w0f, cnt, plist, pwt);
  hipLaunchKernelGGL(plan_k, dim3(1), dim3(64), 0, stream, cnt, workq);
  hipLaunchKernelGGL(ffn_k<1>, dim3(MAXT * (FF / 128)), dim3(256), 0, stream,
                     xb, w1t, b1, (const unsigned short*)nullptr, h, (float*)nullptr,
                     cnt, plist, pwt, workq);
  hipLaunchKernelGGL(ffn_k<2>, dim3(MAXT * (HIDDEN / 128)), dim3(256), 0, stream,
                     xb, w2t, b2, h, (unsigned short*)nullptr, out,
                     cnt, plist, pwt, workq);
}

// Round 14
// 540.408 us; speedup vs baseline: 1.1160x; 1.1160x over previous
//
#include <hip/hip_runtime.h>

#define HIDDEN 1024
#define FF 2048
#define NEXP 8
#define NTOK 16384
#define NPAIR (2 * NTOK)
#define MAXT 264   // sum_e ceil(cnt[e]/128) <= 256 + 8

typedef short short8 __attribute__((ext_vector_type(8)));
typedef unsigned short ushort4v __attribute__((ext_vector_type(4)));
typedef float f32x4 __attribute__((ext_vector_type(4)));

// fp32 -> bf16 bits, round-to-nearest-even
__device__ __forceinline__ unsigned short f2b(float f) {
  union { float f; unsigned int u; } v; v.f = f;
  unsigned int u = v.u;
  return (unsigned short)((u + 0x7fffu + ((u >> 16) & 1u)) >> 16);
}
__device__ __forceinline__ float b2f(unsigned short b) {
  union { unsigned int u; float f; } v; v.u = ((unsigned int)b) << 16;
  return v.f;
}

// async global->LDS, 16B per lane. LDS dest = wave-uniform base + lane*16.
__device__ __forceinline__ void gload16(const unsigned short* g, unsigned short* l) {
  __builtin_amdgcn_global_load_lds(
      (const __attribute__((address_space(1))) unsigned int*)g,
      (__attribute__((address_space(3))) unsigned int*)l,
      16, 0, 0);
}

// counted vmcnt waits: asm memory clobber (compiler fence) + sched fence (rule 18)
#define PIPE_WAIT(n) do { \
    asm volatile("s_waitcnt vmcnt(" #n ")" ::: "memory"); \
    __builtin_amdgcn_sched_barrier(0); \
  } while (0)
// raw barrier that IS a compiler memory fence, plus sched fence
#define ABAR do { \
    asm volatile("s_barrier" ::: "memory"); \
    __builtin_amdgcn_sched_barrier(0); \
  } while (0)

// ---------------- workspace layout (bytes) ----------------
#define W1T_OFF 0ull                                                      // [E][FF][HIDDEN] bf16, 32MB
#define W2T_OFF (W1T_OFF + (unsigned long long)NEXP * FF * HIDDEN * 2)    // [E][HIDDEN][FF] bf16, 32MB
#define H_OFF   (W2T_OFF + (unsigned long long)NEXP * HIDDEN * FF * 2)    // [NPAIR][FF] bf16, 128MB
#define XB_OFF  (H_OFF + (unsigned long long)NPAIR * FF * 2)              // [NTOK][HIDDEN] bf16, 32MB
#define CNT_OFF (XB_OFF + (unsigned long long)NTOK * HIDDEN * 2)          // [E] int
#define PLIST_OFF (CNT_OFF + 256ull)                                      // [E][NTOK] int
#define PW_OFF    (PLIST_OFF + (unsigned long long)NEXP * NTOK * 4)       // [NPAIR] float
#define TOPS_OFF  (PW_OFF + (unsigned long long)NPAIR * 4)                // [NTOK] int
#define W0_OFF    (TOPS_OFF + (unsigned long long)NTOK * 4)               // [NTOK] float
#define WQ_OFF    (W0_OFF + (unsigned long long)NTOK * 4)                 // [MAXT] int
#define YP_OFF    (WQ_OFF + 4096ull)                                      // [NPAIR][HIDDEN] bf16, 67MB
#define WS_NEED   (YP_OFF + (unsigned long long)NPAIR * HIDDEN * 2)

// zero out with our own kernel: hipMemsetAsync inside kernel_launch is NOT
// replayed reliably under graph capture (R10 post-timing re-validation fail).
__global__ void zero_out_k(float4* __restrict__ out) {
  out[(size_t)blockIdx.x * 256 + threadIdx.x] = float4{0.f, 0.f, 0.f, 0.f};
}

__global__ void zero_cnt_k(int* __restrict__ cnt) {
  if (threadIdx.x < NEXP) cnt[threadIdx.x] = 0;
}

// in: [E][R][C] f32  ->  out: [E][C][R] bf16
__global__ void transpose_cast_k(const float* __restrict__ in,
                                 unsigned short* __restrict__ out,
                                 int R, int C) {
  __shared__ float tile[32][33];
  const size_t eoff = (size_t)blockIdx.z * R * C;
  const float* inp = in + eoff;
  unsigned short* outp = out + eoff;
  const int c = threadIdx.x & 31;
  const int r0 = threadIdx.x >> 5;
  const int gr = blockIdx.y * 32, gc = blockIdx.x * 32;
#pragma unroll
  for (int i = 0; i < 4; i++) {
    int r = r0 + i * 8;
    tile[r][c] = inp[(size_t)(gr + r) * C + gc + c];
  }
  __syncthreads();
#pragma unroll
  for (int i = 0; i < 4; i++) {
    int r = r0 + i * 8;
    outp[(size_t)(gc + r) * R + gr + c] = f2b(tile[c][r]);
  }
}

// one wave per token: logits over 8 experts, top-2, renorm; fused x->bf16 cast.
__global__ void router_k(const float* __restrict__ x, const float* __restrict__ rw,
                         const float* __restrict__ rb, int* __restrict__ tops,
                         float* __restrict__ w0f, unsigned short* __restrict__ xb) {
  const int wid = threadIdx.x >> 6;
  const int lane = threadIdx.x & 63;
  const int t = blockIdx.x * 4 + wid;
  const float* xr = x + (size_t)t * HIDDEN;
  float acc[8];
#pragma unroll
  for (int e = 0; e < 8; e++) acc[e] = 0.f;
#pragma unroll
  for (int i = 0; i < 16; i++) {
    int hh = lane + 64 * i;
    float xv = xr[hh];
    const float4* rwp = reinterpret_cast<const float4*>(rw + (size_t)hh * 8);
    float4 a = rwp[0], b = rwp[1];
    acc[0] += xv * a.x; acc[1] += xv * a.y; acc[2] += xv * a.z; acc[3] += xv * a.w;
    acc[4] += xv * b.x; acc[5] += xv * b.y; acc[6] += xv * b.z; acc[7] += xv * b.w;
  }
  // fused cast: x row -> xb row (vectorized, L2-hot after the dot loop)
  {
    const float4* xr4 = reinterpret_cast<const float4*>(xr);
    unsigned short* xbr = xb + (size_t)t * HIDDEN;
#pragma unroll
    for (int i = 0; i < 4; i++) {
      float4 f = xr4[lane + 64 * i];
      ushort4v o;
      o[0] = f2b(f.x); o[1] = f2b(f.y); o[2] = f2b(f.z); o[3] = f2b(f.w);
      *reinterpret_cast<ushort4v*>(&xbr[(lane + 64 * i) * 4]) = o;
    }
  }
#pragma unroll
  for (int off = 32; off; off >>= 1) {
#pragma unroll
    for (int e = 0; e < 8; e++) acc[e] += __shfl_xor(acc[e], off);
  }
  if (lane == 0) {
#pragma unroll
    for (int e = 0; e < 8; e++) acc[e] += rb[e];
    int i0 = 0; float m0 = acc[0];
#pragma unroll
    for (int e = 1; e < 8; e++) if (acc[e] > m0) { m0 = acc[e]; i0 = e; }
    int i1 = -1; float m1 = -1e30f;
#pragma unroll
    for (int e = 0; e < 8; e++) if (e != i0 && acc[e] > m1) { m1 = acc[e]; i1 = e; }
    float w0 = 1.f / (1.f + __expf(m1 - m0));
    tops[t] = i0 | (i1 << 4);
    w0f[t] = w0;
  }
}

// block-aggregated scatter: 256 tokens/block, LDS histogram, 8 global atomics/block
__global__ __launch_bounds__(256)
void scatter_k(const int* __restrict__ tops, const float* __restrict__ w0f,
               int* __restrict__ cnt, int* __restrict__ plist, float* __restrict__ pw) {
  __shared__ int lcnt[NEXP];
  __shared__ int lbase[NEXP];
  const int tid = threadIdx.x;
  const int t = blockIdx.x * 256 + tid;
  if (tid < NEXP) lcnt[tid] = 0;
  __syncthreads();
  const int packed = tops[t];
  const int i0 = packed & 15, i1 = packed >> 4;
  const float w0 = w0f[t];
  const int s0 = atomicAdd(&lcnt[i0], 1);
  const int s1 = atomicAdd(&lcnt[i1], 1);
  __syncthreads();
  if (tid < NEXP) lbase[tid] = atomicAdd(&cnt[tid], lcnt[tid]);
  __syncthreads();
  plist[i0 * NTOK + lbase[i0] + s0] = 2 * t;
  plist[i1 * NTOK + lbase[i1] + s1] = 2 * t + 1;
  pw[2 * t] = w0;
  pw[2 * t + 1] = 1.f - w0;
}

// build compact (expert, 128-row m-tile) work list
__global__ void plan_k(const int* __restrict__ cnt, int* __restrict__ workq) {
  if (threadIdx.x == 0) {
    int idx = 0;
    for (int e = 0; e < NEXP; e++) {
      int nt = (cnt[e] + 127) >> 7;
      for (int m = 0; m < nt; m++) workq[idx++] = (e << 16) | m;
    }
    while (idx < MAXT) workq[idx++] = -1;
  }
}

// combine: out[t] = w0 * ypair[2t] + w1 * ypair[2t+1]  (bf16 in, fp32 out)
// block = 256 thr = 2 tokens (128 thr x 8 elems each)
__global__ __launch_bounds__(256)
void combine_k(const unsigned short* __restrict__ ypair, const float* __restrict__ pw,
               float* __restrict__ out) {
  const int t = blockIdx.x * 2 + (threadIdx.x >> 7);
  const int i = (threadIdx.x & 127) * 8;
  const float w0 = pw[2 * t], w1 = pw[2 * t + 1];
  const short8 y0 = *(const short8*)&ypair[(size_t)(2 * t) * HIDDEN + i];
  const short8 y1 = *(const short8*)&ypair[(size_t)(2 * t + 1) * HIDDEN + i];
  float* orow = out + (size_t)t * HIDDEN + i;
#pragma unroll
  for (int j = 0; j < 8; j++)
    orow[j] = w0 * b2f((unsigned short)y0[j]) + w1 * b2f((unsigned short)y1[j]);
}

// Grouped GEMM, 128x128 tile, 4 waves, BK=32, 3-deep counted-vmcnt pipeline
// (R8/R11-proven skeleton) + 4-slot both-sides LDS XOR swizzle.
// PHASE 1: h[pair] = relu(xb[token] @ w1t[e]^T + b1[e])  (K=1024,N=2048)
// PHASE 2: ypair[pair] = h[pair] @ w2t[e]^T + b2[e]      (K=2048,N=1024)  [YP=1]
//          or atomic out += pw * (...)                   [YP=0 fallback]
template <int PHASE, int YP>
__global__ __launch_bounds__(256, 3)
void ffn_k(const unsigned short* __restrict__ xb, const unsigned short* __restrict__ wT,
           const float* __restrict__ bias, const unsigned short* __restrict__ hin,
           unsigned short* __restrict__ hout, float* __restrict__ out,
           const int* __restrict__ cnt, const int* __restrict__ plist,
           const float* __restrict__ pw, const int* __restrict__ workq) {
  constexpr int K = (PHASE == 1) ? HIDDEN : FF;
  constexpr int N = (PHASE == 1) ? FF : HIDDEN;
  constexpr int NT = K / 32;
  constexpr int NTN = N / 128;
  constexpr int NWG = MAXT * NTN;

  // bijective XCD swizzle (m204): XCD k gets a contiguous wgid chunk
  constexpr int q8 = NWG / 8, r8 = NWG % 8;
  const int bid = blockIdx.x;
  const int xcd = bid & 7, idx = bid >> 3;
  const int wgid = (xcd < r8 ? xcd * (q8 + 1) : r8 * (q8 + 1) + (xcd - r8) * q8) + idx;
  const int mt = wgid / NTN;
  const int n0g = (wgid % NTN) * 128;

  const int w = workq[mt];
  if (w < 0) return;
  const int e = w >> 16;
  const int m0g = (w & 0xffff) * 128;
  const int mcnt = cnt[e];
  const int mrem = mcnt - m0g;

  // triple-buffered linear LDS: 6 x 8 KB = 48 KB
  __shared__ alignas(16) unsigned short As[3][128][32];
  __shared__ alignas(16) unsigned short Bs[3][128][32];
  __shared__ int rowpair[128];

  const int tid = threadIdx.x;
  if (tid < 128) rowpair[tid] = (tid < mrem) ? plist[e * NTOK + m0g + tid] : -1;
  __syncthreads();

  const int wid = tid >> 6;
  const int lane = tid & 63;

  // staging: chunk c (0..7) = LDS rows [c*16, c*16+16). lane l -> row c*16+(l>>2),
  // LDS slot (l&3); GLOBAL slot pre-swizzled: (l&3)^((l>>2)&3). 4 gloads/wave/tile.
  const int sslot = (lane & 3) ^ ((lane >> 2) & 3);
  const int rsub = lane >> 2;
  const unsigned short* wTe = wT + (size_t)e * N * K;

  const unsigned short* gA[2];
  const unsigned short* gB[2];
#pragma unroll
  for (int i = 0; i < 2; i++) {
    const int c = wid + i * 4;
    const int row = c * 16 + rsub;
    int p = rowpair[row];
    if (p < 0) p = 0;  // dummy valid row; its acc rows are never written
    const unsigned short* abase;
    if constexpr (PHASE == 1) abase = xb + (size_t)(p >> 1) * HIDDEN;
    else                      abase = hin + (size_t)p * FF;
    gA[i] = abase + sslot * 8;
    gB[i] = wTe + (size_t)(n0g + row) * K + sslot * 8;
  }

  const int wr = (wid >> 1) * 64;
  const int wc = (wid & 1) * 64;
  const int fr = lane & 15;
  const int fg = lane >> 4;
  const int fsw = (fr & 3);   // read-side swizzle term

  f32x4 acc[4][4];
#pragma unroll
  for (int i = 0; i < 4; i++)
#pragma unroll
    for (int j = 0; j < 4; j++) acc[i][j] = f32x4{0.f, 0.f, 0.f, 0.f};

  // ---- prologue: tiles 0,1,2 -> bufs 0,1,2 (12 loads in flight per wave) ----
#pragma unroll
  for (int b = 0; b < 3; b++) {
#pragma unroll
    for (int i = 0; i < 2; i++) {
      const int c = wid + i * 4;
      gload16(gA[i] + b * 32, &As[b][c * 16][0]);
      gload16(gB[i] + b * 32, &Bs[b][c * 16][0]);
    }
  }

  int cur = 0;
  for (int t = 0; t < NT; ++t) {
    if (t < NT - 2)       PIPE_WAIT(8);  // tile t done; t+1,t+2 stay in flight
    else if (t == NT - 2) PIPE_WAIT(4);
    else                  PIPE_WAIT(0);
    ABAR;  // all waves' tile-t loads now visible

    short8 af[4], bf[4];
#pragma unroll
    for (int mi = 0; mi < 4; mi++)
      af[mi] = *(const short8*)&As[cur][wr + mi * 16 + fr][(fg ^ fsw) * 8];
#pragma unroll
    for (int ni = 0; ni < 4; ni++)
      bf[ni] = *(const short8*)&Bs[cur][wc + ni * 16 + fr][(fg ^ fsw) * 8];
#pragma unroll
    for (int mi = 0; mi < 4; mi++)
#pragma unroll
      for (int ni = 0; ni < 4; ni++)
        acc[mi][ni] = __builtin_amdgcn_mfma_f32_16x16x32_bf16(af[mi], bf[ni], acc[mi][ni], 0, 0, 0);

    ABAR;  // all waves done READING buf[cur]; safe to overwrite

    if (t + 3 < NT) {
      const int kt = (t + 3) * 32;
#pragma unroll
      for (int i = 0; i < 2; i++) {
        const int c = wid + i * 4;
        gload16(gA[i] + kt, &As[cur][c * 16][0]);
        gload16(gB[i] + kt, &Bs[cur][c * 16][0]);
      }
    }
    cur = (cur == 2) ? 0 : cur + 1;
  }

  // ---- epilogue ----
  float bv[4];
#pragma unroll
  for (int ni = 0; ni < 4; ni++) bv[ni] = bias[(size_t)e * N + n0g + wc + ni * 16 + fr];

#pragma unroll
  for (int mi = 0; mi < 4; mi++) {
#pragma unroll
    for (int r = 0; r < 4; r++) {
      int m = wr + mi * 16 + fg * 4 + r;
      if (m >= mrem) continue;
      int p = rowpair[m];
      if constexpr (PHASE == 1) {
        unsigned short* hr = hout + (size_t)p * FF + n0g;
#pragma unroll
        for (int ni = 0; ni < 4; ni++) {
          float v = acc[mi][ni][r] + bv[ni];
          hr[wc + ni * 16 + fr] = f2b(fmaxf(v, 0.f));
        }
      } else if constexpr (YP == 1) {
        // unweighted per-pair row, bf16; combine_k applies pw
        unsigned short* yr = hout + (size_t)p * HIDDEN + n0g;
#pragma unroll
        for (int ni = 0; ni < 4; ni++) {
          float v = acc[mi][ni][r] + bv[ni];
          yr[wc + ni * 16 + fr] = f2b(v);
        }
      } else {
        float wgt = pw[p];
        float* orow = out + (size_t)(p >> 1) * HIDDEN + n0g;
#pragma unroll
        for (int ni = 0; ni < 4; ni++) {
          float v = (acc[mi][ni][r] + bv[ni]) * wgt;
          atomicAdd(&orow[wc + ni * 16 + fr], v);
        }
      }
    }
  }
}

extern "C" void kernel_launch(void* const* d_in, const int* in_sizes, int n_in,
                              void* d_out, int out_size, void* d_ws, size_t ws_size,
                              hipStream_t stream) {
  const float* x  = (const float*)d_in[0];
  const float* rw = (const float*)d_in[1];
  const float* rb = (const float*)d_in[2];
  const float* w1 = (const float*)d_in[3];
  const float* b1 = (const float*)d_in[4];
  const float* w2 = (const float*)d_in[5];
  const float* b2 = (const float*)d_in[6];
  float* out = (float*)d_out;
  char* ws = (char*)d_ws;

  unsigned short* w1t = (unsigned short*)(ws + W1T_OFF);
  unsigned short* w2t = (unsigned short*)(ws + W2T_OFF);
  unsigned short* h   = (unsigned short*)(ws + H_OFF);
  unsigned short* xb  = (unsigned short*)(ws + XB_OFF);
  int* cnt   = (int*)(ws + CNT_OFF);
  int* plist = (int*)(ws + PLIST_OFF);
  float* pwt = (float*)(ws + PW_OFF);
  int* tops  = (int*)(ws + TOPS_OFF);
  float* w0f = (float*)(ws + W0_OFF);
  int* workq = (int*)(ws + WQ_OFF);
  unsigned short* ypair = (unsigned short*)(ws + YP_OFF);

  const bool use_yp = (ws_size >= WS_NEED);  // host-side constant: graph-stable

  hipLaunchKernelGGL(zero_cnt_k, dim3(1), dim3(64), 0, stream, cnt);
  if (!use_yp)
    hipLaunchKernelGGL(zero_out_k, dim3(16384), dim3(256), 0, stream, (float4*)out);
  hipLaunchKernelGGL(transpose_cast_k, dim3(FF / 32, HIDDEN / 32, NEXP), dim3(256), 0, stream,
                     w1, w1t, HIDDEN, FF);
  hipLaunchKernelGGL(transpose_cast_k, dim3(HIDDEN / 32, FF / 32, NEXP), dim3(256), 0, stream,
                     w2, w2t, FF, HIDDEN);
  hipLaunchKernelGGL(router_k, dim3(NTOK / 4), dim3(256), 0, stream, x, rw, rb, tops, w0f, xb);
  hipLaunchKernelGGL(scatter_k, dim3(NTOK / 256), dim3(256), 0, stream, tops, w0f, cnt, plist, pwt);
  hipLaunchKernelGGL(plan_k, dim3(1), dim3(64), 0, stream, cnt, workq);
  hipLaunchKernelGGL((ffn_k<1, 0>), dim3(MAXT * (FF / 128)), dim3(256), 0, stream,
                     xb, w1t, b1, (const unsigned short*)nullptr, h, (float*)nullptr,
                     cnt, plist, pwt, workq);
  if (use_yp) {
    hipLaunchKernelGGL((ffn_k<2, 1>), dim3(MAXT * (HIDDEN / 128)), dim3(256), 0, stream,
                       xb, w2t, b2, h, ypair, (float*)nullptr,
                       cnt, plist, pwt, workq);
    hipLaunchKernelGGL(combine_k, dim3(NTOK / 2), dim3(256), 0, stream, ypair, pwt, out);
  } else {
    hipLaunchKernelGGL((ffn_k<2, 0>), dim3(MAXT * (HIDDEN / 128)), dim3(256), 0, stream,
                       xb, w2t, b2, h, (unsigned short*)nullptr, out,
                       cnt, plist, pwt, workq);
  }
}

// Round 15
// 465.788 us; speedup vs baseline: 1.2947x; 1.1602x over previous
//
#include <hip/hip_runtime.h>

#define HIDDEN 1024
#define FF 2048
#define NEXP 8
#define NTOK 16384
#define NPAIR (2 * NTOK)
#define MAXT 264   // sum_e ceil(cnt[e]/128) <= 256 + 8

typedef short short8 __attribute__((ext_vector_type(8)));
typedef unsigned short ushort4v __attribute__((ext_vector_type(4)));
typedef float f32x4 __attribute__((ext_vector_type(4)));

// fp32 -> bf16 bits, round-to-nearest-even
__device__ __forceinline__ unsigned short f2b(float f) {
  union { float f; unsigned int u; } v; v.f = f;
  unsigned int u = v.u;
  return (unsigned short)((u + 0x7fffu + ((u >> 16) & 1u)) >> 16);
}
__device__ __forceinline__ float b2f(unsigned short b) {
  union { unsigned int u; float f; } v; v.u = ((unsigned int)b) << 16;
  return v.f;
}

// async global->LDS, 16B per lane. LDS dest = wave-uniform base + lane*16.
__device__ __forceinline__ void gload16(const unsigned short* g, unsigned short* l) {
  __builtin_amdgcn_global_load_lds(
      (const __attribute__((address_space(1))) unsigned int*)g,
      (__attribute__((address_space(3))) unsigned int*)l,
      16, 0, 0);
}

// counted vmcnt waits: asm memory clobber (compiler fence) + sched fence (rule 18)
#define PIPE_WAIT(n) do { \
    asm volatile("s_waitcnt vmcnt(" #n ")" ::: "memory"); \
    __builtin_amdgcn_sched_barrier(0); \
  } while (0)
// raw barrier that IS a compiler memory fence, plus sched fence
#define ABAR do { \
    asm volatile("s_barrier" ::: "memory"); \
    __builtin_amdgcn_sched_barrier(0); \
  } while (0)

// ---------------- workspace layout (bytes) ----------------
// Ordered so that w1t and xb (both DEAD after ffn1) are adjacent; ypair
// aliases exactly that 64MB region. Total footprint unchanged vs R11.
#define W2T_OFF 0ull                                                      // [E][HIDDEN][FF] bf16, 32MB
#define W1T_OFF (W2T_OFF + (unsigned long long)NEXP * HIDDEN * FF * 2)    // [E][FF][HIDDEN] bf16, 32MB
#define XB_OFF  (W1T_OFF + (unsigned long long)NEXP * FF * HIDDEN * 2)    // [NTOK][HIDDEN] bf16, 32MB
#define H_OFF   (XB_OFF + (unsigned long long)NTOK * HIDDEN * 2)          // [NPAIR][FF] bf16, 128MB
#define CNT_OFF (H_OFF + (unsigned long long)NPAIR * FF * 2)              // [E] int
#define PLIST_OFF (CNT_OFF + 256ull)                                      // [E][NTOK] int
#define PW_OFF    (PLIST_OFF + (unsigned long long)NEXP * NTOK * 4)       // [NPAIR] float
#define TOPS_OFF  (PW_OFF + (unsigned long long)NPAIR * 4)                // [NTOK] int
#define W0_OFF    (TOPS_OFF + (unsigned long long)NTOK * 4)               // [NTOK] float
#define WQ_OFF    (W0_OFF + (unsigned long long)NTOK * 4)                 // [MAXT] int
#define YP_OFF    W1T_OFF   // [NPAIR][HIDDEN] bf16, 64MB — aliases w1t+xb (dead after ffn1)
#define WS_NEED   (WQ_OFF + 4096ull)

// zero out with our own kernel: hipMemsetAsync inside kernel_launch is NOT
// replayed reliably under graph capture (R10 post-timing re-validation fail).
// Only needed on the atomic fallback path now.
__global__ void zero_out_k(float4* __restrict__ out) {
  out[(size_t)blockIdx.x * 256 + threadIdx.x] = float4{0.f, 0.f, 0.f, 0.f};
}

// in: [E][R][C] f32  ->  out: [E][C][R] bf16
__global__ void transpose_cast_k(const float* __restrict__ in,
                                 unsigned short* __restrict__ out,
                                 int R, int C) {
  __shared__ float tile[32][33];
  const size_t eoff = (size_t)blockIdx.z * R * C;
  const float* inp = in + eoff;
  unsigned short* outp = out + eoff;
  const int c = threadIdx.x & 31;
  const int r0 = threadIdx.x >> 5;
  const int gr = blockIdx.y * 32, gc = blockIdx.x * 32;
#pragma unroll
  for (int i = 0; i < 4; i++) {
    int r = r0 + i * 8;
    tile[r][c] = inp[(size_t)(gr + r) * C + gc + c];
  }
  __syncthreads();
#pragma unroll
  for (int i = 0; i < 4; i++) {
    int r = r0 + i * 8;
    outp[(size_t)(gc + r) * R + gr + c] = f2b(tile[c][r]);
  }
}

// one wave per token: logits over 8 experts, top-2, renorm; fused x->bf16 cast.
// Also zeroes cnt (block 0) — runs before scatter via kernel boundary.
__global__ void router_k(const float* __restrict__ x, const float* __restrict__ rw,
                         const float* __restrict__ rb, int* __restrict__ tops,
                         float* __restrict__ w0f, unsigned short* __restrict__ xb,
                         int* __restrict__ cnt) {
  if (blockIdx.x == 0 && threadIdx.x < NEXP) cnt[threadIdx.x] = 0;
  const int wid = threadIdx.x >> 6;
  const int lane = threadIdx.x & 63;
  const int t = blockIdx.x * 4 + wid;
  const float* xr = x + (size_t)t * HIDDEN;
  float acc[8];
#pragma unroll
  for (int e = 0; e < 8; e++) acc[e] = 0.f;
#pragma unroll
  for (int i = 0; i < 16; i++) {
    int hh = lane + 64 * i;
    float xv = xr[hh];
    const float4* rwp = reinterpret_cast<const float4*>(rw + (size_t)hh * 8);
    float4 a = rwp[0], b = rwp[1];
    acc[0] += xv * a.x; acc[1] += xv * a.y; acc[2] += xv * a.z; acc[3] += xv * a.w;
    acc[4] += xv * b.x; acc[5] += xv * b.y; acc[6] += xv * b.z; acc[7] += xv * b.w;
  }
  // fused cast: x row -> xb row (vectorized, L2-hot after the dot loop)
  {
    const float4* xr4 = reinterpret_cast<const float4*>(xr);
    unsigned short* xbr = xb + (size_t)t * HIDDEN;
#pragma unroll
    for (int i = 0; i < 4; i++) {
      float4 f = xr4[lane + 64 * i];
      ushort4v o;
      o[0] = f2b(f.x); o[1] = f2b(f.y); o[2] = f2b(f.z); o[3] = f2b(f.w);
      *reinterpret_cast<ushort4v*>(&xbr[(lane + 64 * i) * 4]) = o;
    }
  }
#pragma unroll
  for (int off = 32; off; off >>= 1) {
#pragma unroll
    for (int e = 0; e < 8; e++) acc[e] += __shfl_xor(acc[e], off);
  }
  if (lane == 0) {
#pragma unroll
    for (int e = 0; e < 8; e++) acc[e] += rb[e];
    int i0 = 0; float m0 = acc[0];
#pragma unroll
    for (int e = 1; e < 8; e++) if (acc[e] > m0) { m0 = acc[e]; i0 = e; }
    int i1 = -1; float m1 = -1e30f;
#pragma unroll
    for (int e = 0; e < 8; e++) if (e != i0 && acc[e] > m1) { m1 = acc[e]; i1 = e; }
    float w0 = 1.f / (1.f + __expf(m1 - m0));
    tops[t] = i0 | (i1 << 4);
    w0f[t] = w0;
  }
}

// block-aggregated scatter: 256 tokens/block, LDS histogram, 8 global atomics/block
__global__ __launch_bounds__(256)
void scatter_k(const int* __restrict__ tops, const float* __restrict__ w0f,
               int* __restrict__ cnt, int* __restrict__ plist, float* __restrict__ pw) {
  __shared__ int lcnt[NEXP];
  __shared__ int lbase[NEXP];
  const int tid = threadIdx.x;
  const int t = blockIdx.x * 256 + tid;
  if (tid < NEXP) lcnt[tid] = 0;
  __syncthreads();
  const int packed = tops[t];
  const int i0 = packed & 15, i1 = packed >> 4;
  const float w0 = w0f[t];
  const int s0 = atomicAdd(&lcnt[i0], 1);
  const int s1 = atomicAdd(&lcnt[i1], 1);
  __syncthreads();
  if (tid < NEXP) lbase[tid] = atomicAdd(&cnt[tid], lcnt[tid]);
  __syncthreads();
  plist[i0 * NTOK + lbase[i0] + s0] = 2 * t;
  plist[i1 * NTOK + lbase[i1] + s1] = 2 * t + 1;
  pw[2 * t] = w0;
  pw[2 * t + 1] = 1.f - w0;
}

// build compact (expert, 128-row m-tile) work list
__global__ void plan_k(const int* __restrict__ cnt, int* __restrict__ workq) {
  if (threadIdx.x == 0) {
    int idx = 0;
    for (int e = 0; e < NEXP; e++) {
      int nt = (cnt[e] + 127) >> 7;
      for (int m = 0; m < nt; m++) workq[idx++] = (e << 16) | m;
    }
    while (idx < MAXT) workq[idx++] = -1;
  }
}

// combine: out[t] = w0 * ypair[2t] + w1 * ypair[2t+1]  (bf16 in, fp32 out)
// Sole writer of out => no zero pass, no atomics, replay-deterministic.
__global__ __launch_bounds__(256)
void combine_k(const unsigned short* __restrict__ ypair, const float* __restrict__ pw,
               float* __restrict__ out) {
  const int t = blockIdx.x * 2 + (threadIdx.x >> 7);
  const int i = (threadIdx.x & 127) * 8;
  const float w0 = pw[2 * t], w1 = pw[2 * t + 1];
  const short8 y0 = *(const short8*)&ypair[(size_t)(2 * t) * HIDDEN + i];
  const short8 y1 = *(const short8*)&ypair[(size_t)(2 * t + 1) * HIDDEN + i];
  float* orow = out + (size_t)t * HIDDEN + i;
#pragma unroll
  for (int j = 0; j < 8; j++)
    orow[j] = w0 * b2f((unsigned short)y0[j]) + w1 * b2f((unsigned short)y1[j]);
}

// Grouped GEMM, 128x128 tile, 4 waves, BK=32, 3-deep counted-vmcnt pipeline
// (R8/R11-proven skeleton) + 4-slot both-sides LDS XOR swizzle.
// PHASE 1: h[pair] = relu(xb[token] @ w1t[e]^T + b1[e])  (K=1024,N=2048)
// PHASE 2: ypair[pair] = h[pair] @ w2t[e]^T + b2[e]      (K=2048,N=1024)  [YP=1]
//          or atomic out += pw * (...)                   [YP=0 fallback]
template <int PHASE, int YP>
__global__ __launch_bounds__(256, 3)
void ffn_k(const unsigned short* __restrict__ xb, const unsigned short* __restrict__ wT,
           const float* __restrict__ bias, const unsigned short* __restrict__ hin,
           unsigned short* __restrict__ hout, float* __restrict__ out,
           const int* __restrict__ cnt, const int* __restrict__ plist,
           const float* __restrict__ pw, const int* __restrict__ workq) {
  constexpr int K = (PHASE == 1) ? HIDDEN : FF;
  constexpr int N = (PHASE == 1) ? FF : HIDDEN;
  constexpr int NT = K / 32;
  constexpr int NTN = N / 128;
  constexpr int NWG = MAXT * NTN;

  // bijective XCD swizzle (m204): XCD k gets a contiguous wgid chunk
  constexpr int q8 = NWG / 8, r8 = NWG % 8;
  const int bid = blockIdx.x;
  const int xcd = bid & 7, idx = bid >> 3;
  const int wgid = (xcd < r8 ? xcd * (q8 + 1) : r8 * (q8 + 1) + (xcd - r8) * q8) + idx;
  const int mt = wgid / NTN;
  const int n0g = (wgid % NTN) * 128;

  const int w = workq[mt];
  if (w < 0) return;
  const int e = w >> 16;
  const int m0g = (w & 0xffff) * 128;
  const int mcnt = cnt[e];
  const int mrem = mcnt - m0g;

  // triple-buffered linear LDS: 6 x 8 KB = 48 KB
  __shared__ alignas(16) unsigned short As[3][128][32];
  __shared__ alignas(16) unsigned short Bs[3][128][32];
  __shared__ int rowpair[128];

  const int tid = threadIdx.x;
  if (tid < 128) rowpair[tid] = (tid < mrem) ? plist[e * NTOK + m0g + tid] : -1;
  __syncthreads();

  const int wid = tid >> 6;
  const int lane = tid & 63;

  // staging: chunk c (0..7) = LDS rows [c*16, c*16+16). lane l -> row c*16+(l>>2),
  // LDS slot (l&3); GLOBAL slot pre-swizzled: (l&3)^((l>>2)&3). 4 gloads/wave/tile.
  const int sslot = (lane & 3) ^ ((lane >> 2) & 3);
  const int rsub = lane >> 2;
  const unsigned short* wTe = wT + (size_t)e * N * K;

  const unsigned short* gA[2];
  const unsigned short* gB[2];
#pragma unroll
  for (int i = 0; i < 2; i++) {
    const int c = wid + i * 4;
    const int row = c * 16 + rsub;
    int p = rowpair[row];
    if (p < 0) p = 0;  // dummy valid row; its acc rows are never written
    const unsigned short* abase;
    if constexpr (PHASE == 1) abase = xb + (size_t)(p >> 1) * HIDDEN;
    else                      abase = hin + (size_t)p * FF;
    gA[i] = abase + sslot * 8;
    gB[i] = wTe + (size_t)(n0g + row) * K + sslot * 8;
  }

  const int wr = (wid >> 1) * 64;
  const int wc = (wid & 1) * 64;
  const int fr = lane & 15;
  const int fg = lane >> 4;
  const int fsw = (fr & 3);   // read-side swizzle term

  f32x4 acc[4][4];
#pragma unroll
  for (int i = 0; i < 4; i++)
#pragma unroll
    for (int j = 0; j < 4; j++) acc[i][j] = f32x4{0.f, 0.f, 0.f, 0.f};

  // ---- prologue: tiles 0,1,2 -> bufs 0,1,2 (12 loads in flight per wave) ----
#pragma unroll
  for (int b = 0; b < 3; b++) {
#pragma unroll
    for (int i = 0; i < 2; i++) {
      const int c = wid + i * 4;
      gload16(gA[i] + b * 32, &As[b][c * 16][0]);
      gload16(gB[i] + b * 32, &Bs[b][c * 16][0]);
    }
  }

  int cur = 0;
  for (int t = 0; t < NT; ++t) {
    if (t < NT - 2)       PIPE_WAIT(8);  // tile t done; t+1,t+2 stay in flight
    else if (t == NT - 2) PIPE_WAIT(4);
    else                  PIPE_WAIT(0);
    ABAR;  // all waves' tile-t loads now visible

    short8 af[4], bf[4];
#pragma unroll
    for (int mi = 0; mi < 4; mi++)
      af[mi] = *(const short8*)&As[cur][wr + mi * 16 + fr][(fg ^ fsw) * 8];
#pragma unroll
    for (int ni = 0; ni < 4; ni++)
      bf[ni] = *(const short8*)&Bs[cur][wc + ni * 16 + fr][(fg ^ fsw) * 8];
#pragma unroll
    for (int mi = 0; mi < 4; mi++)
#pragma unroll
      for (int ni = 0; ni < 4; ni++)
        acc[mi][ni] = __builtin_amdgcn_mfma_f32_16x16x32_bf16(af[mi], bf[ni], acc[mi][ni], 0, 0, 0);

    ABAR;  // all waves done READING buf[cur]; safe to overwrite

    if (t + 3 < NT) {
      const int kt = (t + 3) * 32;
#pragma unroll
      for (int i = 0; i < 2; i++) {
        const int c = wid + i * 4;
        gload16(gA[i] + kt, &As[cur][c * 16][0]);
        gload16(gB[i] + kt, &Bs[cur][c * 16][0]);
      }
    }
    cur = (cur == 2) ? 0 : cur + 1;
  }

  // ---- epilogue ----
  float bv[4];
#pragma unroll
  for (int ni = 0; ni < 4; ni++) bv[ni] = bias[(size_t)e * N + n0g + wc + ni * 16 + fr];

#pragma unroll
  for (int mi = 0; mi < 4; mi++) {
#pragma unroll
    for (int r = 0; r < 4; r++) {
      int m = wr + mi * 16 + fg * 4 + r;
      if (m >= mrem) continue;
      int p = rowpair[m];
      if constexpr (PHASE == 1) {
        unsigned short* hr = hout + (size_t)p * FF + n0g;
#pragma unroll
        for (int ni = 0; ni < 4; ni++) {
          float v = acc[mi][ni][r] + bv[ni];
          hr[wc + ni * 16 + fr] = f2b(fmaxf(v, 0.f));
        }
      } else if constexpr (YP == 1) {
        // unweighted per-pair row, bf16; combine_k applies pw
        unsigned short* yr = hout + (size_t)p * HIDDEN + n0g;
#pragma unroll
        for (int ni = 0; ni < 4; ni++) {
          float v = acc[mi][ni][r] + bv[ni];
          yr[wc + ni * 16 + fr] = f2b(v);
        }
      } else {
        float wgt = pw[p];
        float* orow = out + (size_t)(p >> 1) * HIDDEN + n0g;
#pragma unroll
        for (int ni = 0; ni < 4; ni++) {
          float v = (acc[mi][ni][r] + bv[ni]) * wgt;
          atomicAdd(&orow[wc + ni * 16 + fr], v);
        }
      }
    }
  }
}

extern "C" void kernel_launch(void* const* d_in, const int* in_sizes, int n_in,
                              void* d_out, int out_size, void* d_ws, size_t ws_size,
                              hipStream_t stream) {
  const float* x  = (const float*)d_in[0];
  const float* rw = (const float*)d_in[1];
  const float* rb = (const float*)d_in[2];
  const float* w1 = (const float*)d_in[3];
  const float* b1 = (const float*)d_in[4];
  const float* w2 = (const float*)d_in[5];
  const float* b2 = (const float*)d_in[6];
  float* out = (float*)d_out;
  char* ws = (char*)d_ws;

  unsigned short* w2t = (unsigned short*)(ws + W2T_OFF);
  unsigned short* w1t = (unsigned short*)(ws + W1T_OFF);
  unsigned short* xb  = (unsigned short*)(ws + XB_OFF);
  unsigned short* h   = (unsigned short*)(ws + H_OFF);
  int* cnt   = (int*)(ws + CNT_OFF);
  int* plist = (int*)(ws + PLIST_OFF);
  float* pwt = (float*)(ws + PW_OFF);
  int* tops  = (int*)(ws + TOPS_OFF);
  float* w0f = (float*)(ws + W0_OFF);
  int* workq = (int*)(ws + WQ_OFF);
  unsigned short* ypair = (unsigned short*)(ws + YP_OFF);  // aliases w1t+xb (dead after ffn1)

  const bool use_yp = (ws_size >= WS_NEED);  // == old footprint; true whenever R11 fit

  if (!use_yp)
    hipLaunchKernelGGL(zero_out_k, dim3(16384), dim3(256), 0, stream, (float4*)out);
  hipLaunchKernelGGL(transpose_cast_k, dim3(FF / 32, HIDDEN / 32, NEXP), dim3(256), 0, stream,
                     w1, w1t, HIDDEN, FF);
  hipLaunchKernelGGL(transpose_cast_k, dim3(HIDDEN / 32, FF / 32, NEXP), dim3(256), 0, stream,
                     w2, w2t, FF, HIDDEN);
  hipLaunchKernelGGL(router_k, dim3(NTOK / 4), dim3(256), 0, stream, x, rw, rb, tops, w0f, xb, cnt);
  hipLaunchKernelGGL(scatter_k, dim3(NTOK / 256), dim3(256), 0, stream, tops, w0f, cnt, plist, pwt);
  hipLaunchKernelGGL(plan_k, dim3(1), dim3(64), 0, stream, cnt, workq);
  hipLaunchKernelGGL((ffn_k<1, 0>), dim3(MAXT * (FF / 128)), dim3(256), 0, stream,
                     xb, w1t, b1, (const unsigned short*)nullptr, h, (float*)nullptr,
                     cnt, plist, pwt, workq);
  if (use_yp) {
    hipLaunchKernelGGL((ffn_k<2, 1>), dim3(MAXT * (HIDDEN / 128)), dim3(256), 0, stream,
                       xb, w2t, b2, h, ypair, (float*)nullptr,
                       cnt, plist, pwt, workq);
    hipLaunchKernelGGL(combine_k, dim3(NTOK / 2), dim3(256), 0, stream, ypair, pwt, out);
  } else {
    hipLaunchKernelGGL((ffn_k<2, 0>), dim3(MAXT * (HIDDEN / 128)), dim3(256), 0, stream,
                       xb, w2t, b2, h, (unsigned short*)nullptr, out,
                       cnt, plist, pwt, workq);
  }
}